// Round 9
// baseline (25.066 us; speedup 1.0000x reference)
//
#include <hip/hip_runtime.h>
#include <stdint.h>

// ---------------------------------------------------------------------------
// SelectiveDropout, fused single-kernel, compile-time RNG table, depth-32.
//   out[b,d] = in[b,d] * scale[d]
//   scale[d] = 1 unless d in neuron_indices; listed columns get
//   (u < 0.1) ? 0 : 1/0.9, u = jax.random.uniform(key(42), (2048,)),
//   duplicates last-write-wins.
//
// keep_bit(i) depends only on i -> constexpr Threefry table (64 words),
// integer-folded compare: u < 0.1f <=> (bits>>9) <= 838860. Bit-exact vs
// jax verified rounds 1-8 (absmax 0.0).
//
// Round-9 geometry: 256 blocks x 512 threads x 32 f32x4/thread
// (R7: 1024x512x8 = 27.0us, R8: 512x512x16 = 25.0us). One block per CU,
// single generation, 256 redundant heads, 32 loads in flight per thread
// (same 256KB/CU in flight). __launch_bounds__(512,2): VGPR cap 256
// (v[32] = 128 + ~30 overhead ~ 160, no spill expected).
//
// Block b covers scale cols [(b&1)*2048, +2048): tid&1023 = (b&1)*512+t.
// Input loads all issued before the head; LDS-only barriers (raw s_barrier
// + lgkmcnt(0), never __syncthreads which drains vmcnt). Round-3 lesson:
// no nontemporal hints anywhere (L3 residency across replays is the win;
// NT stores would also force HBM writebacks every replay).
// ---------------------------------------------------------------------------

#define D_DIM 4096

typedef float f32x4 __attribute__((ext_vector_type(4)));
typedef int i32x4 __attribute__((ext_vector_type(4)));

// ---- compile-time Threefry-2x32(20 rounds, key=(0,42)) keep-bit table ----
constexpr uint32_t rotl_c(uint32_t v, int n) {
  return (v << n) | (v >> (32 - n));
}

constexpr uint32_t tf_bits(uint32_t i) {
  const uint32_t ks0 = 0u, ks1 = 42u, ks2 = 0u ^ 42u ^ 0x1BD11BDAu;
  uint32_t x0 = 0u + ks0, x1 = i + ks1;
  x0 += x1; x1 = rotl_c(x1, 13); x1 ^= x0;
  x0 += x1; x1 = rotl_c(x1, 15); x1 ^= x0;
  x0 += x1; x1 = rotl_c(x1, 26); x1 ^= x0;
  x0 += x1; x1 = rotl_c(x1, 6);  x1 ^= x0;
  x0 += ks1; x1 += ks2 + 1u;
  x0 += x1; x1 = rotl_c(x1, 17); x1 ^= x0;
  x0 += x1; x1 = rotl_c(x1, 29); x1 ^= x0;
  x0 += x1; x1 = rotl_c(x1, 16); x1 ^= x0;
  x0 += x1; x1 = rotl_c(x1, 24); x1 ^= x0;
  x0 += ks2; x1 += ks0 + 2u;
  x0 += x1; x1 = rotl_c(x1, 13); x1 ^= x0;
  x0 += x1; x1 = rotl_c(x1, 15); x1 ^= x0;
  x0 += x1; x1 = rotl_c(x1, 26); x1 ^= x0;
  x0 += x1; x1 = rotl_c(x1, 6);  x1 ^= x0;
  x0 += ks0; x1 += ks1 + 3u;
  x0 += x1; x1 = rotl_c(x1, 17); x1 ^= x0;
  x0 += x1; x1 = rotl_c(x1, 29); x1 ^= x0;
  x0 += x1; x1 = rotl_c(x1, 16); x1 ^= x0;
  x0 += x1; x1 = rotl_c(x1, 24); x1 ^= x0;
  x0 += ks1; x1 += ks2 + 4u;
  x0 += x1; x1 = rotl_c(x1, 13); x1 ^= x0;
  x0 += x1; x1 = rotl_c(x1, 15); x1 ^= x0;
  x0 += x1; x1 = rotl_c(x1, 26); x1 ^= x0;
  x0 += x1; x1 = rotl_c(x1, 6);  x1 ^= x0;
  x0 += ks2; x1 += ks0 + 5u;
  return x0 ^ x1;
}

// keep <=> mantissa (bits>>9) >= 838861  (== !(u < 0.1f), exact)
constexpr uint32_t keep_word(int w) {
  uint32_t r = 0;
  for (int b = 0; b < 32; ++b) {
    if ((tf_bits((uint32_t)(w * 32 + b)) >> 9) >= 838861u) r |= (1u << b);
  }
  return r;
}

struct KeepTab {
  uint32_t w[64];
};
constexpr KeepTab make_tab() {
  KeepTab t{};
  for (int i = 0; i < 64; ++i) t.w[i] = keep_word(i);
  return t;
}
__device__ __constant__ KeepTab KEEP = make_tab();

// runtime keep for the generic fallback (any i)
__device__ __forceinline__ int keep_bit_rt(uint32_t i) {
  const uint32_t ks0 = 0u, ks1 = 42u, ks2 = 0u ^ 42u ^ 0x1BD11BDAu;
  uint32_t x0 = 0u + ks0, x1 = i + ks1;
#define TF4(a, b, c, d)                           \
  x0 += x1; x1 = (x1 << a) | (x1 >> (32 - a)); x1 ^= x0; \
  x0 += x1; x1 = (x1 << b) | (x1 >> (32 - b)); x1 ^= x0; \
  x0 += x1; x1 = (x1 << c) | (x1 >> (32 - c)); x1 ^= x0; \
  x0 += x1; x1 = (x1 << d) | (x1 >> (32 - d)); x1 ^= x0;
  TF4(13, 15, 26, 6)  x0 += ks1; x1 += ks2 + 1u;
  TF4(17, 29, 16, 24) x0 += ks2; x1 += ks0 + 2u;
  TF4(13, 15, 26, 6)  x0 += ks0; x1 += ks1 + 3u;
  TF4(17, 29, 16, 24) x0 += ks1; x1 += ks2 + 4u;
  TF4(13, 15, 26, 6)  x0 += ks2; x1 += ks0 + 5u;
#undef TF4
  return ((x0 ^ x1) >> 9) >= 838861u ? 1 : 0;
}

__global__ __launch_bounds__(512, 2) void selective_dropout_fused(
    const f32x4* __restrict__ in, const int* __restrict__ idx, int n,
    f32x4* __restrict__ out, int total4) {
  __shared__ int lds[D_DIM];  // fast path uses [0..2047]; fallback all 4096
  const int t = threadIdx.x;
  const int tid = blockIdx.x * 512 + t;
  const int stride = gridDim.x * 512;
  const float inv_keep = (float)(1.0 / (1.0 - 0.1));

  if (n == 2048 && total4 == stride * 32 && gridDim.x == 256) {
    int* packed = lds;                // [2048] max (i<<1|keep); -1 untouched
    const int half = blockIdx.x & 1;  // block covers cols [half*2048, +2048)

    // --- A: idx slice + keep-table word first (oldest vmem) ---
    i32x4 c = ((const i32x4*)idx)[t];  // i = 4t..4t+3
    uint32_t kw = KEEP.w[t >> 3];      // one word covers 4t..4t+3
    __builtin_amdgcn_sched_barrier(0);

    // --- B: issue all 32 input loads (stay in flight through the head) ---
    f32x4 v[32];
#pragma unroll
    for (int k = 0; k < 32; ++k) v[k] = in[tid + k * stride];
    __builtin_amdgcn_sched_barrier(0);

    // --- C: init winner array (1 ds_write_b128 per thread) ---
    {
      i32x4 m1;
      m1[0] = -1; m1[1] = -1; m1[2] = -1; m1[3] = -1;
      ((i32x4*)packed)[t] = m1;
    }
    asm volatile("s_waitcnt lgkmcnt(0)" ::: "memory");
    __builtin_amdgcn_s_barrier();  // LDS-only; input loads stay in flight

    // --- D: direct filtered scatter (keep bit from table, no hash) ---
#pragma unroll
    for (int k = 0; k < 4; ++k) {
      int i = t * 4 + k;
      int d = c[k];
      if ((d >> 11) == half) {
        int keep = (int)((kw >> (i & 31)) & 1u);
        atomicMax(&packed[d & 2047], (i << 1) | keep);
      }
    }
    asm volatile("s_waitcnt lgkmcnt(0)" ::: "memory");
    __builtin_amdgcn_s_barrier();

    // --- E: per-thread scale: local f32x4 index == t ---
    i32x4 pk = ((i32x4*)packed)[t];
    f32x4 s;
#pragma unroll
    for (int j = 0; j < 4; ++j)
      s[j] = (pk[j] < 0) ? 1.0f : ((pk[j] & 1) ? inv_keep : 0.0f);

    // --- F: multiply + store as loads land (vmcnt drains in order) ---
#pragma unroll
    for (int k = 0; k < 32; ++k) {
      v[k] *= s;
      out[tid + k * stride] = v[k];
    }
  } else {
    // Generic fallback: full 4096-entry scatter, grid-stride apply.
    int* packed = lds;
    for (int d = t; d < D_DIM; d += blockDim.x) packed[d] = -1;
    __syncthreads();
    for (int i = t; i < n; i += blockDim.x) {
      atomicMax(&packed[idx[i]], (i << 1) | keep_bit_rt((uint32_t)i));
    }
    __syncthreads();
    const int gstride = gridDim.x * blockDim.x;
    for (int e = blockIdx.x * blockDim.x + t; e < total4; e += gstride) {
      i32x4 pk = ((i32x4*)packed)[e & (D_DIM / 4 - 1)];
      f32x4 s;
#pragma unroll
      for (int j = 0; j < 4; ++j)
        s[j] = (pk[j] < 0) ? 1.0f : ((pk[j] & 1) ? inv_keep : 0.0f);
      f32x4 x = in[e];
      x *= s;
      out[e] = x;
    }
  }
}

extern "C" void kernel_launch(void* const* d_in, const int* in_sizes, int n_in,
                              void* d_out, int out_size, void* d_ws, size_t ws_size,
                              hipStream_t stream) {
  const float* in = (const float*)d_in[0];
  const int* idx = (const int*)d_in[1];
  float* out = (float*)d_out;

  const int n_idx = in_sizes[1];    // 2048
  const int total = in_sizes[0];    // B*D = 16,777,216
  const int total4 = total / 4;

  const int blocks = 256;  // 512 threads, 32 f32x4/thread: 1 block/CU
  hipLaunchKernelGGL(selective_dropout_fused, dim3(blocks), dim3(512), 0,
                     stream, (const f32x4*)in, idx, n_idx, (f32x4*)out,
                     total4);
}